// Round 1
// baseline (263.694 us; speedup 1.0000x reference)
//
#include <hip/hip_runtime.h>
#include <hip/hip_bf16.h>

// Problem constants (from setup_inputs): bs=2, seq=2048, d_model=512, heads=8, d_k=64, WINDOW=2
#define SEQ 2048
#define DM  512
#define BS  2
#define NH  8
#define DK  64

// ---------------- fp32 tiled GEMM: C = A @ B + bias ----------------
// A: MxK row-major, B: KxN row-major, bias: N. M,N,K multiples of 64/64/16.
#define BM 64
#define BN 64
#define BK 16

__global__ __launch_bounds__(256) void gemm_bias(const float* __restrict__ A,
                                                 const float* __restrict__ B,
                                                 const float* __restrict__ bias,
                                                 float* __restrict__ C,
                                                 int M, int N, int K)
{
    __shared__ float As[BK][BM];   // transposed: As[k][m]
    __shared__ float Bs[BK][BN];

    const int tid = threadIdx.x;
    const int tx = tid & 15;       // 0..15 col group (4 cols each)
    const int ty = tid >> 4;       // 0..15 row group (4 rows each)
    const int m0 = blockIdx.y * BM;
    const int n0 = blockIdx.x * BN;

    // staging indices
    const int ar = tid >> 2;       // 0..63: row within A tile
    const int ac = tid & 3;        // which float4 within 16-wide K strip
    const int br = tid >> 4;       // 0..15: k row within B tile
    const int bc = tid & 15;       // which float4 within 64-wide N strip

    float acc[4][4] = {};

    for (int k0 = 0; k0 < K; k0 += BK) {
        float4 av = *(const float4*)(A + (size_t)(m0 + ar) * K + k0 + ac * 4);
        float4 bv = *(const float4*)(B + (size_t)(k0 + br) * N + n0 + bc * 4);
        As[ac * 4 + 0][ar] = av.x;
        As[ac * 4 + 1][ar] = av.y;
        As[ac * 4 + 2][ar] = av.z;
        As[ac * 4 + 3][ar] = av.w;
        *(float4*)(&Bs[br][bc * 4]) = bv;
        __syncthreads();
        #pragma unroll
        for (int kk = 0; kk < BK; ++kk) {
            float4 a4 = *(const float4*)(&As[kk][ty * 4]);
            float4 b4 = *(const float4*)(&Bs[kk][tx * 4]);
            float ra[4] = {a4.x, a4.y, a4.z, a4.w};
            float rb[4] = {b4.x, b4.y, b4.z, b4.w};
            #pragma unroll
            for (int i = 0; i < 4; ++i)
                #pragma unroll
                for (int j = 0; j < 4; ++j)
                    acc[i][j] += ra[i] * rb[j];
        }
        __syncthreads();
    }

    float4 bv4 = *(const float4*)(bias + n0 + tx * 4);
    float rb4[4] = {bv4.x, bv4.y, bv4.z, bv4.w};
    #pragma unroll
    for (int i = 0; i < 4; ++i) {
        int m = m0 + ty * 4 + i;
        float4 outv;
        outv.x = acc[i][0] + rb4[0];
        outv.y = acc[i][1] + rb4[1];
        outv.z = acc[i][2] + rb4[2];
        outv.w = acc[i][3] + rb4[3];
        *(float4*)(C + (size_t)m * N + n0 + tx * 4) = outv;
    }
}

// ---------------- V column-sum: vsum[b*DM + c] = sum_s Vp[b,s,c] ----------------
__global__ __launch_bounds__(256) void vsum_kernel(const float* __restrict__ Vp,
                                                   float* __restrict__ vsum)
{
    const int col = blockIdx.x * 256 + threadIdx.x;   // 0..BS*DM-1
    const int b = col >> 9;     // /DM
    const int c = col & 511;    // %DM
    const int chunk = SEQ / 16; // 128
    const float* p = Vp + ((size_t)b * SEQ + (size_t)blockIdx.y * chunk) * DM + c;
    float s = 0.f;
    for (int k = 0; k < chunk; ++k) s += p[(size_t)k * DM];
    atomicAdd(vsum + col, s);
}

// ---------------- band attention with full-row-softmax algebra ----------------
// out_row = (vsum + sum_band (e^s - 1) v_k) / (seq + sum_band (e^s - 1))
// Out may alias Qp: each block reads only its own Q slice before writing it.
__global__ __launch_bounds__(256) void attn_kernel(const float* Qp,
                                                   const float* __restrict__ Kp,
                                                   const float* __restrict__ Vp,
                                                   const float* __restrict__ vsum,
                                                   float* Out)
{
    const int d = threadIdx.x;                      // 0..63
    const int qpos = blockIdx.x * 4 + threadIdx.y;  // 0..SEQ-1
    const int h = blockIdx.y & 7;
    const int b = blockIdx.y >> 3;
    const int col = h * DK + d;
    const size_t rowbase = (size_t)b * SEQ;

    const float qd = Qp[(rowbase + qpos) * DM + col];
    float acc = vsum[b * DM + col];
    float den = (float)SEQ;

    const int klo = max(qpos - 4, 0);
    const int khi = min(qpos + 4, SEQ - 1);
    for (int k = klo; k <= khi; ++k) {
        float p = qd * Kp[(rowbase + k) * DM + col];
        #pragma unroll
        for (int off = 32; off >= 1; off >>= 1)
            p += __shfl_xor(p, off, 64);
        const int mn = min(qpos, k), mx = max(qpos, k);
        const float cnt = (float)(min(mn + 2, SEQ - 1) - max(mx - 2, 0) + 1);
        const float w = expf(p * 0.125f * cnt) - 1.0f;
        acc += w * Vp[(rowbase + k) * DM + col];
        den += w;
    }
    Out[(rowbase + qpos) * DM + col] = acc / den;
}

extern "C" void kernel_launch(void* const* d_in, const int* in_sizes, int n_in,
                              void* d_out, int out_size, void* d_ws, size_t ws_size,
                              hipStream_t stream) {
    const float* q  = (const float*)d_in[0];
    const float* k  = (const float*)d_in[1];
    const float* v  = (const float*)d_in[2];
    const float* Wq = (const float*)d_in[3];
    const float* bq = (const float*)d_in[4];
    const float* Wk = (const float*)d_in[5];
    const float* bk = (const float*)d_in[6];
    const float* Wv = (const float*)d_in[7];
    const float* bv = (const float*)d_in[8];
    const float* Wo = (const float*)d_in[9];
    const float* bo = (const float*)d_in[10];

    const int M = BS * SEQ;   // 4096
    const int N = DM;         // 512
    const int K = DM;         // 512

    float* ws = (float*)d_ws;
    float* Qp   = ws;                       // M*DM
    float* Kp   = ws + (size_t)M * DM;      // M*DM
    float* Vp   = ws + (size_t)2 * M * DM;  // M*DM
    float* vsum = ws + (size_t)3 * M * DM;  // BS*DM

    dim3 gg(N / BN, M / BM);   // (8, 64)
    gemm_bias<<<gg, 256, 0, stream>>>(q, Wq, bq, Qp, M, N, K);
    gemm_bias<<<gg, 256, 0, stream>>>(k, Wk, bk, Kp, M, N, K);
    gemm_bias<<<gg, 256, 0, stream>>>(v, Wv, bv, Vp, M, N, K);

    hipMemsetAsync(vsum, 0, (size_t)BS * DM * sizeof(float), stream);
    vsum_kernel<<<dim3(BS * DM / 256, 16), 256, 0, stream>>>(Vp, vsum);

    // Out aliases Qp (safe: per-block read-before-write on disjoint slices)
    attn_kernel<<<dim3(SEQ / 4, BS * NH), dim3(64, 4), 0, stream>>>(Qp, Kp, Vp, vsum, Qp);

    gemm_bias<<<gg, 256, 0, stream>>>(Qp, Wo, bo, (float*)d_out, M, N, K);
}

// Round 2
// 154.138 us; speedup vs baseline: 1.7108x; 1.7108x over previous
//
#include <hip/hip_runtime.h>
#include <hip/hip_bf16.h>

// bs=2, seq=2048, d_model=512, heads=8, d_k=64, WINDOW=2
#define SEQ 2048
#define DM  512
#define BS  2
#define NH  8
#define DK  64
#define MROWS (BS * SEQ)   // 4096

// MFMA GEMM tile config (m97 recipe)
#define GM 128
#define GN 128
#define GK 32

typedef __attribute__((ext_vector_type(8))) short bf16x8;
typedef __attribute__((ext_vector_type(4))) float f32x4;

__device__ __forceinline__ unsigned short f2bf(float f) {
    // round-to-nearest-even fp32 -> bf16 (finite inputs)
    unsigned int u = __float_as_uint(f);
    u += 0x7fff + ((u >> 16) & 1);
    return (unsigned short)(u >> 16);
}

// async global->LDS, 16B per lane. LDS dest must be wave-uniform base + lane*16.
#define GLDS16(g, l) __builtin_amdgcn_global_load_lds( \
    (const __attribute__((address_space(1))) void*)(g), \
    (__attribute__((address_space(3))) void*)(unsigned int)(unsigned long long)(l), 16, 0, 0)

// ---------------- fp32 -> bf16 convert for q,k,v (z-batched) ----------------
__global__ __launch_bounds__(256) void cvt_qkv(const float* __restrict__ q,
                                               const float* __restrict__ k,
                                               const float* __restrict__ v,
                                               unsigned short* __restrict__ qb,
                                               unsigned short* __restrict__ kb,
                                               unsigned short* __restrict__ vb)
{
    const float* src = (blockIdx.y == 0) ? q : (blockIdx.y == 1) ? k : v;
    unsigned short* dst = (blockIdx.y == 0) ? qb : (blockIdx.y == 1) ? kb : vb;
    const size_t idx = ((size_t)blockIdx.x * 256 + threadIdx.x) * 8;
    float4 v0 = *(const float4*)(src + idx);
    float4 v1 = *(const float4*)(src + idx + 4);
    ushort4 o0, o1;
    o0.x = f2bf(v0.x); o0.y = f2bf(v0.y); o0.z = f2bf(v0.z); o0.w = f2bf(v0.w);
    o1.x = f2bf(v1.x); o1.y = f2bf(v1.y); o1.z = f2bf(v1.z); o1.w = f2bf(v1.w);
    *(ushort4*)(dst + idx) = o0;
    *(ushort4*)(dst + idx + 4) = o1;
}

// ---------------- weight transpose + convert: W[k][n] f32 -> WT[n][k] bf16 ----------------
__global__ __launch_bounds__(256) void transpose_w(const float* __restrict__ W0, const float* __restrict__ W1,
                                                   const float* __restrict__ W2, const float* __restrict__ W3,
                                                   unsigned short* __restrict__ T0, unsigned short* __restrict__ T1,
                                                   unsigned short* __restrict__ T2, unsigned short* __restrict__ T3)
{
    __shared__ float tile[32][33];
    const float* W = (blockIdx.z == 0) ? W0 : (blockIdx.z == 1) ? W1 : (blockIdx.z == 2) ? W2 : W3;
    unsigned short* T = (blockIdx.z == 0) ? T0 : (blockIdx.z == 1) ? T1 : (blockIdx.z == 2) ? T2 : T3;
    const int n0 = blockIdx.x * 32, k0 = blockIdx.y * 32;
    const int tx = threadIdx.x & 31;       // 0..31
    const int ty = threadIdx.x >> 5;       // 0..7
    #pragma unroll
    for (int r = 0; r < 32; r += 8)
        tile[ty + r][tx] = W[(size_t)(k0 + ty + r) * DM + n0 + tx];
    __syncthreads();
    #pragma unroll
    for (int r = 0; r < 32; r += 8)
        T[(size_t)(n0 + ty + r) * DM + k0 + tx] = f2bf(tile[tx][ty + r]);
}

// ---------------- bf16 MFMA GEMM core: C(f32, 4096x512) = A(bf16, 4096x512) @ BT(bf16, 512x512)^T + bias ----------------
__device__ __forceinline__ void gemm_core(const unsigned short* __restrict__ A,
                                          const unsigned short* __restrict__ BT,
                                          const float* __restrict__ bias,
                                          float* __restrict__ C)
{
    __shared__ unsigned short As[GM * GK];   // [row][k], 8 KB
    __shared__ unsigned short Bs[GN * GK];   // [n][k],   8 KB

    const int tid  = threadIdx.x;
    const int lane = tid & 63;
    const int wave = tid >> 6;
    const int wm = (wave & 1) * 64;
    const int wn = (wave >> 1) * 64;
    const int m0 = blockIdx.y * GM;
    const int n0 = blockIdx.x * GN;
    const int l15 = lane & 15;
    const int q8  = (lane >> 4) * 8;

    f32x4 acc[4][4];
    #pragma unroll
    for (int i = 0; i < 4; ++i)
        #pragma unroll
        for (int j = 0; j < 4; ++j)
            acc[i][j] = (f32x4){0.f, 0.f, 0.f, 0.f};

    // staging: 512 chunks of 16B per tile; thread handles chunks tid and tid+256
    const int c0 = tid, c1 = tid + 256;
    const unsigned short* ga0 = A  + (size_t)(m0 + (c0 >> 2)) * DM + (c0 & 3) * 8;
    const unsigned short* ga1 = A  + (size_t)(m0 + (c1 >> 2)) * DM + (c1 & 3) * 8;
    const unsigned short* gb0 = BT + (size_t)(n0 + (c0 >> 2)) * DM + (c0 & 3) * 8;
    const unsigned short* gb1 = BT + (size_t)(n0 + (c1 >> 2)) * DM + (c1 & 3) * 8;
    unsigned short* la0 = &As[c0 * 8];
    unsigned short* la1 = &As[c1 * 8];
    unsigned short* lb0 = &Bs[c0 * 8];
    unsigned short* lb1 = &Bs[c1 * 8];

    for (int k0 = 0; k0 < DM; k0 += GK) {
        GLDS16(ga0 + k0, la0);
        GLDS16(ga1 + k0, la1);
        GLDS16(gb0 + k0, lb0);
        GLDS16(gb1 + k0, lb1);
        __syncthreads();

        bf16x8 af[4], bfr[4];
        #pragma unroll
        for (int i = 0; i < 4; ++i)
            af[i] = *(const bf16x8*)&As[(wm + i * 16 + l15) * GK + q8];
        #pragma unroll
        for (int j = 0; j < 4; ++j)
            bfr[j] = *(const bf16x8*)&Bs[(wn + j * 16 + l15) * GK + q8];
        #pragma unroll
        for (int i = 0; i < 4; ++i)
            #pragma unroll
            for (int j = 0; j < 4; ++j)
                acc[i][j] = __builtin_amdgcn_mfma_f32_16x16x32_bf16(af[i], bfr[j], acc[i][j], 0, 0, 0);
        __syncthreads();
    }

    // epilogue: C/D layout col=lane&15, row=(lane>>4)*4+reg
    #pragma unroll
    for (int j = 0; j < 4; ++j) {
        const int col = n0 + wn + j * 16 + l15;
        const float bv = bias[col];
        #pragma unroll
        for (int i = 0; i < 4; ++i) {
            const int rbase = m0 + wm + i * 16 + (lane >> 4) * 4;
            #pragma unroll
            for (int r = 0; r < 4; ++r)
                C[(size_t)(rbase + r) * DM + col] = acc[i][j][r] + bv;
        }
    }
}

__global__ __launch_bounds__(256) void gemm_qkv(const unsigned short* qb, const unsigned short* kb, const unsigned short* vb,
                                                const unsigned short* WqT, const unsigned short* WkT, const unsigned short* WvT,
                                                const float* bq, const float* bk, const float* bv,
                                                float* Qp, float* Kp, float* Vp)
{
    const unsigned short* A;  const unsigned short* BT;  const float* bias;  float* C;
    if (blockIdx.z == 0)      { A = qb; BT = WqT; bias = bq; C = Qp; }
    else if (blockIdx.z == 1) { A = kb; BT = WkT; bias = bk; C = Kp; }
    else                      { A = vb; BT = WvT; bias = bv; C = Vp; }
    gemm_core(A, BT, bias, C);
}

__global__ __launch_bounds__(256) void gemm_out(const unsigned short* A, const unsigned short* BT,
                                                const float* bias, float* C)
{
    gemm_core(A, BT, bias, C);
}

// ---------------- V column-sum: vsum[b*DM + c] = sum_s Vp[b,s,c] ----------------
__global__ __launch_bounds__(256) void vsum_kernel(const float* __restrict__ Vp,
                                                   float* __restrict__ vsum)
{
    const int col = blockIdx.x * 256 + threadIdx.x;   // 0..BS*DM-1
    const int b = col >> 9;
    const int c = col & 511;
    const int chunk = SEQ / 16;
    const float* p = Vp + ((size_t)b * SEQ + (size_t)blockIdx.y * chunk) * DM + c;
    float s = 0.f;
    for (int k = 0; k < chunk; ++k) s += p[(size_t)k * DM];
    atomicAdd(vsum + col, s);
}

// ---------------- band attention, full-row-softmax algebra, bf16 concat out ----------------
// out_row = (vsum + sum_band (e^s - 1) v_k) / (seq + sum_band (e^s - 1))
__global__ __launch_bounds__(256) void attn_kernel(const float* __restrict__ Qp,
                                                   const float* __restrict__ Kp,
                                                   const float* __restrict__ Vp,
                                                   const float* __restrict__ vsum,
                                                   unsigned short* __restrict__ concat)
{
    const int d = threadIdx.x;                      // 0..63
    const int qpos = blockIdx.x * 4 + threadIdx.y;
    const int h = blockIdx.y & 7;
    const int b = blockIdx.y >> 3;
    const int col = h * DK + d;
    const size_t rowbase = (size_t)b * SEQ;

    const float qd = Qp[(rowbase + qpos) * DM + col];
    float acc = vsum[b * DM + col];
    float den = (float)SEQ;

    const int klo = max(qpos - 4, 0);
    const int khi = min(qpos + 4, SEQ - 1);
    for (int k = klo; k <= khi; ++k) {
        float p = qd * Kp[(rowbase + k) * DM + col];
        #pragma unroll
        for (int off = 32; off >= 1; off >>= 1)
            p += __shfl_xor(p, off, 64);
        const int mn = min(qpos, k), mx = max(qpos, k);
        const float cnt = (float)(min(mn + 2, SEQ - 1) - max(mx - 2, 0) + 1);
        const float w = expf(p * 0.125f * cnt) - 1.0f;
        acc += w * Vp[(rowbase + k) * DM + col];
        den += w;
    }
    concat[(rowbase + qpos) * DM + col] = f2bf(acc / den);
}

extern "C" void kernel_launch(void* const* d_in, const int* in_sizes, int n_in,
                              void* d_out, int out_size, void* d_ws, size_t ws_size,
                              hipStream_t stream) {
    const float* q  = (const float*)d_in[0];
    const float* k  = (const float*)d_in[1];
    const float* v  = (const float*)d_in[2];
    const float* Wq = (const float*)d_in[3];
    const float* bq = (const float*)d_in[4];
    const float* Wk = (const float*)d_in[5];
    const float* bk = (const float*)d_in[6];
    const float* Wv = (const float*)d_in[7];
    const float* bv = (const float*)d_in[8];
    const float* Wo = (const float*)d_in[9];
    const float* bo = (const float*)d_in[10];

    const size_t NE = (size_t)MROWS * DM;  // 2,097,152

    float* ws = (float*)d_ws;
    float* Qp   = ws;
    float* Kp   = Qp + NE;
    float* Vp   = Kp + NE;
    float* vsum = Vp + NE;                 // 1024 floats
    unsigned short* qb     = (unsigned short*)(vsum + 1024);
    unsigned short* kb     = qb + NE;
    unsigned short* vb     = kb + NE;
    unsigned short* WqT    = vb + NE;
    unsigned short* WkT    = WqT + DM * DM;
    unsigned short* WvT    = WkT + DM * DM;
    unsigned short* WoT    = WvT + DM * DM;
    unsigned short* concat = WoT + DM * DM;

    // 1. convert activations to bf16
    cvt_qkv<<<dim3((unsigned)(NE / (256 * 8)), 3), 256, 0, stream>>>(q, k, v, qb, kb, vb);

    // 2. transpose + convert weights to [n][k] bf16
    transpose_w<<<dim3(16, 16, 4), 256, 0, stream>>>(Wq, Wk, Wv, Wo, WqT, WkT, WvT, WoT);

    // 3. fused Q/K/V projection GEMMs (384 blocks)
    gemm_qkv<<<dim3(DM / GN, MROWS / GM, 3), 256, 0, stream>>>(qb, kb, vb, WqT, WkT, WvT,
                                                               bq, bk, bv, Qp, Kp, Vp);

    // 4. V column sums
    hipMemsetAsync(vsum, 0, (size_t)BS * DM * sizeof(float), stream);
    vsum_kernel<<<dim3(BS * DM / 256, 16), 256, 0, stream>>>(Vp, vsum);

    // 5. band attention -> bf16 concat
    attn_kernel<<<dim3(SEQ / 4, BS * NH), dim3(64, 4), 0, stream>>>(Qp, Kp, Vp, vsum, concat);

    // 6. output projection
    gemm_out<<<dim3(DM / GN, MROWS / GM), 256, 0, stream>>>(concat, WoT, bo, (float*)d_out);
}

// Round 3
// 147.864 us; speedup vs baseline: 1.7834x; 1.0424x over previous
//
#include <hip/hip_runtime.h>
#include <hip/hip_bf16.h>

// bs=2, seq=2048, d_model=512, heads=8, d_k=64, WINDOW=2
#define SEQ 2048
#define DM  512
#define BS  2
#define NH  8
#define DK  64
#define MROWS (BS * SEQ)   // 4096
#define GK 32

typedef __attribute__((ext_vector_type(8))) short bf16x8;
typedef __attribute__((ext_vector_type(4))) float f32x4;

__device__ __forceinline__ unsigned short f2bf(float f) {
    unsigned int u = __float_as_uint(f);
    u += 0x7fff + ((u >> 16) & 1);
    return (unsigned short)(u >> 16);
}

// async global->LDS, 16B per lane. LDS dest must be wave-uniform base + lane*16.
#define GLDS16(g, l) __builtin_amdgcn_global_load_lds( \
    (const __attribute__((address_space(1))) void*)(g), \
    (__attribute__((address_space(3))) void*)(unsigned int)(unsigned long long)(l), 16, 0, 0)

// ---------------- prep: fp32->bf16 cvt of q,k,v (blocks 0..3071) + weight transpose (3072..4095) ----------------
__global__ __launch_bounds__(256) void prep_kernel(const float* __restrict__ q,
                                                   const float* __restrict__ k,
                                                   const float* __restrict__ v,
                                                   const float* __restrict__ Wq, const float* __restrict__ Wk,
                                                   const float* __restrict__ Wv, const float* __restrict__ Wo,
                                                   unsigned short* __restrict__ qb,
                                                   unsigned short* __restrict__ kb,
                                                   unsigned short* __restrict__ vb,
                                                   unsigned short* __restrict__ WqT, unsigned short* __restrict__ WkT,
                                                   unsigned short* __restrict__ WvT, unsigned short* __restrict__ WoT)
{
    __shared__ float tile[32][33];
    const int bid = blockIdx.x;
    if (bid < 3072) {
        const int z = bid >> 10;
        const int blk = bid & 1023;
        const float* src = (z == 0) ? q : (z == 1) ? k : v;
        unsigned short* dst = (z == 0) ? qb : (z == 1) ? kb : vb;
        const size_t idx = ((size_t)blk * 256 + threadIdx.x) * 8;
        float4 v0 = *(const float4*)(src + idx);
        float4 v1 = *(const float4*)(src + idx + 4);
        ushort4 o0, o1;
        o0.x = f2bf(v0.x); o0.y = f2bf(v0.y); o0.z = f2bf(v0.z); o0.w = f2bf(v0.w);
        o1.x = f2bf(v1.x); o1.y = f2bf(v1.y); o1.z = f2bf(v1.z); o1.w = f2bf(v1.w);
        *(ushort4*)(dst + idx) = o0;
        *(ushort4*)(dst + idx + 4) = o1;
    } else {
        const int t = bid - 3072;
        const int z = t >> 8;
        const int tl = t & 255;
        const float* W = (z == 0) ? Wq : (z == 1) ? Wk : (z == 2) ? Wv : Wo;
        unsigned short* T = (z == 0) ? WqT : (z == 1) ? WkT : (z == 2) ? WvT : WoT;
        const int n0 = (tl & 15) * 32, k0 = (tl >> 4) * 32;
        const int tx = threadIdx.x & 31;
        const int ty = threadIdx.x >> 5;
        #pragma unroll
        for (int r = 0; r < 32; r += 8)
            tile[ty + r][tx] = W[(size_t)(k0 + ty + r) * DM + n0 + tx];
        __syncthreads();
        #pragma unroll
        for (int r = 0; r < 32; r += 8)
            T[(size_t)(n0 + ty + r) * DM + k0 + tx] = f2bf(tile[tx][ty + r]);
    }
}

// ---------------- templated bf16 MFMA GEMM core ----------------
// C(f32, M x 512) = A(bf16, M x 512) @ BT(bf16, 512 x 512)^T + bias
// TGM x TGN block tile, 4 waves in (TGM/(WMT*16)) x (TGN/(WNT*16)) grid, GK=32.
template<int TGM, int TGN, int WMT, int WNT>
__device__ __forceinline__ void gemm_core(const unsigned short* __restrict__ A,
                                          const unsigned short* __restrict__ BT,
                                          const float* __restrict__ bias,
                                          float* __restrict__ C)
{
    __shared__ unsigned short S[(TGM + TGN) * GK];   // As then Bs, both [row][k]

    const int tid  = threadIdx.x;
    const int lane = tid & 63;
    const int wave = tid >> 6;
    constexpr int WAVES_M = TGM / (WMT * 16);
    const int wm = (wave % WAVES_M) * (WMT * 16);
    const int wn = (wave / WAVES_M) * (WNT * 16);
    const int m0 = blockIdx.y * TGM;
    const int n0 = blockIdx.x * TGN;
    const int l15 = lane & 15;
    const int q8  = (lane >> 4) * 8;

    f32x4 acc[WMT][WNT];
    #pragma unroll
    for (int i = 0; i < WMT; ++i)
        #pragma unroll
        for (int j = 0; j < WNT; ++j)
            acc[i][j] = (f32x4){0.f, 0.f, 0.f, 0.f};

    constexpr int NCH = (TGM + TGN) * 4;   // 16B chunks per GK-tile
    constexpr int NIT = NCH / 256;
    const unsigned short* gp[NIT];
    unsigned short* lp[NIT];
    #pragma unroll
    for (int it = 0; it < NIT; ++it) {
        const int c = tid + it * 256;
        if (c < TGM * 4)
            gp[it] = A + (size_t)(m0 + (c >> 2)) * DM + (c & 3) * 8;
        else {
            const int cb = c - TGM * 4;
            gp[it] = BT + (size_t)(n0 + (cb >> 2)) * DM + (cb & 3) * 8;
        }
        lp[it] = &S[c * 8];
    }

    for (int k0 = 0; k0 < DM; k0 += GK) {
        #pragma unroll
        for (int it = 0; it < NIT; ++it)
            GLDS16(gp[it] + k0, lp[it]);
        __syncthreads();

        bf16x8 af[WMT], bfr[WNT];
        #pragma unroll
        for (int i = 0; i < WMT; ++i)
            af[i] = *(const bf16x8*)&S[(wm + i * 16 + l15) * GK + q8];
        #pragma unroll
        for (int j = 0; j < WNT; ++j)
            bfr[j] = *(const bf16x8*)&S[(TGM + wn + j * 16 + l15) * GK + q8];
        #pragma unroll
        for (int i = 0; i < WMT; ++i)
            #pragma unroll
            for (int j = 0; j < WNT; ++j)
                acc[i][j] = __builtin_amdgcn_mfma_f32_16x16x32_bf16(af[i], bfr[j], acc[i][j], 0, 0, 0);
        __syncthreads();
    }

    // epilogue: C/D layout col=lane&15, row=(lane>>4)*4+reg
    #pragma unroll
    for (int j = 0; j < WNT; ++j) {
        const int col = n0 + wn + j * 16 + l15;
        const float bv = bias[col];
        #pragma unroll
        for (int i = 0; i < WMT; ++i) {
            const int rbase = m0 + wm + i * 16 + (lane >> 4) * 4;
            #pragma unroll
            for (int r = 0; r < 4; ++r)
                C[(size_t)(rbase + r) * DM + col] = acc[i][j][r] + bv;
        }
    }
}

// qkv: 128x64 tile, grid (8, 32, 3) = 768 blocks (3/CU), wave = 64x32
__global__ __launch_bounds__(256) void gemm_qkv(const unsigned short* qb, const unsigned short* kb, const unsigned short* vb,
                                                const unsigned short* WqT, const unsigned short* WkT, const unsigned short* WvT,
                                                const float* bq, const float* bk, const float* bv,
                                                float* Qp, float* Kp, float* Vp)
{
    const unsigned short* A;  const unsigned short* BT;  const float* bias;  float* C;
    if (blockIdx.z == 0)      { A = qb; BT = WqT; bias = bq; C = Qp; }
    else if (blockIdx.z == 1) { A = kb; BT = WkT; bias = bk; C = Kp; }
    else                      { A = vb; BT = WvT; bias = bv; C = Vp; }
    gemm_core<128, 64, 4, 2>(A, BT, bias, C);
}

// out: 64x64 tile, grid (8, 64) = 512 blocks (2/CU), wave = 32x32
__global__ __launch_bounds__(256) void gemm_out(const unsigned short* A, const unsigned short* BT,
                                                const float* bias, float* C)
{
    gemm_core<64, 64, 2, 2>(A, BT, bias, C);
}

// ---------------- V column-sum: vsum[b*DM + c] = sum_s Vp[b,s,c] ----------------
__global__ __launch_bounds__(256) void vsum_kernel(const float* __restrict__ Vp,
                                                   float* __restrict__ vsum)
{
    const int col = blockIdx.x * 256 + threadIdx.x;   // 0..BS*DM-1
    const int b = col >> 9;
    const int c = col & 511;
    const int chunk = SEQ / 16;
    const float* p = Vp + ((size_t)b * SEQ + (size_t)blockIdx.y * chunk) * DM + c;
    float s = 0.f;
    for (int k = 0; k < chunk; ++k) s += p[(size_t)k * DM];
    atomicAdd(vsum + col, s);
}

// ---------------- band attention, full-row-softmax algebra, bf16 concat out ----------------
// out_row = (vsum + sum_band (e^s - 1) v_k) / (seq + sum_band (e^s - 1))
// Static 9-tap band, unrolled; interleaved 64-lane butterfly reductions for ILP.
__global__ __launch_bounds__(256) void attn_kernel(const float* __restrict__ Qp,
                                                   const float* __restrict__ Kp,
                                                   const float* __restrict__ Vp,
                                                   const float* __restrict__ vsum,
                                                   unsigned short* __restrict__ concat)
{
    const int d = threadIdx.x;                      // 0..63
    const int qpos = blockIdx.x * 4 + threadIdx.y;
    const int h = blockIdx.y & 7;
    const int b = blockIdx.y >> 3;
    const int col = h * DK + d;
    const size_t rowbase = (size_t)b * SEQ;
    const float* Kcol = Kp + rowbase * DM + col;
    const float* Vcol = Vp + rowbase * DM + col;

    const float qd = Qp[(rowbase + qpos) * DM + col];
    float acc = vsum[b * DM + col];
    float den = (float)SEQ;

    float p[9], vv[9], cw[9];
    #pragma unroll
    for (int j = 0; j < 9; ++j) {
        const int k = qpos - 4 + j;
        const int kc = min(max(k, 0), SEQ - 1);
        p[j]  = qd * Kcol[(size_t)kc * DM];
        vv[j] = Vcol[(size_t)kc * DM];
        const int mn = min(qpos, k);
        const int mx = qpos + k - mn;
        const float cnt = (float)(min(mn + 2, SEQ - 1) - max(mx - 2, 0) + 1);
        cw[j] = (k >= 0 && k < SEQ) ? cnt * 0.125f : 0.0f;
    }
    #pragma unroll
    for (int off = 32; off >= 1; off >>= 1)
        #pragma unroll
        for (int j = 0; j < 9; ++j)
            p[j] += __shfl_xor(p[j], off, 64);
    #pragma unroll
    for (int j = 0; j < 9; ++j) {
        const float w = expf(p[j] * cw[j]) - 1.0f;   // cw==0 -> w==0 exactly
        acc += w * vv[j];
        den += w;
    }
    concat[(rowbase + qpos) * DM + col] = f2bf(acc / den);
}

extern "C" void kernel_launch(void* const* d_in, const int* in_sizes, int n_in,
                              void* d_out, int out_size, void* d_ws, size_t ws_size,
                              hipStream_t stream) {
    const float* q  = (const float*)d_in[0];
    const float* k  = (const float*)d_in[1];
    const float* v  = (const float*)d_in[2];
    const float* Wq = (const float*)d_in[3];
    const float* bq = (const float*)d_in[4];
    const float* Wk = (const float*)d_in[5];
    const float* bk = (const float*)d_in[6];
    const float* Wv = (const float*)d_in[7];
    const float* bv = (const float*)d_in[8];
    const float* Wo = (const float*)d_in[9];
    const float* bo = (const float*)d_in[10];

    const size_t NE = (size_t)MROWS * DM;  // 2,097,152

    float* ws = (float*)d_ws;
    float* Qp   = ws;
    float* Kp   = Qp + NE;
    float* Vp   = Kp + NE;
    float* vsum = Vp + NE;                 // 1024 floats
    unsigned short* qb     = (unsigned short*)(vsum + 1024);
    unsigned short* kb     = qb + NE;
    unsigned short* vb     = kb + NE;
    unsigned short* WqT    = vb + NE;
    unsigned short* WkT    = WqT + DM * DM;
    unsigned short* WvT    = WkT + DM * DM;
    unsigned short* WoT    = WvT + DM * DM;
    unsigned short* concat = WoT + DM * DM;

    // 1. cvt q/k/v to bf16 + transpose/convert weights (one dispatch)
    prep_kernel<<<4096, 256, 0, stream>>>(q, k, v, Wq, Wk, Wv, Wo,
                                          qb, kb, vb, WqT, WkT, WvT, WoT);

    // 2. fused Q/K/V projection GEMMs (768 blocks, 3/CU)
    gemm_qkv<<<dim3(DM / 64, MROWS / 128, 3), 256, 0, stream>>>(qb, kb, vb, WqT, WkT, WvT,
                                                                bq, bk, bv, Qp, Kp, Vp);

    // 3. V column sums
    hipMemsetAsync(vsum, 0, (size_t)BS * DM * sizeof(float), stream);
    vsum_kernel<<<dim3(BS * DM / 256, 16), 256, 0, stream>>>(Vp, vsum);

    // 4. band attention -> bf16 concat
    attn_kernel<<<dim3(SEQ / 4, BS * NH), dim3(64, 4), 0, stream>>>(Qp, Kp, Vp, vsum, concat);

    // 5. output projection (512 blocks, 2/CU)
    gemm_out<<<dim3(DM / 64, MROWS / 64), 256, 0, stream>>>(concat, WoT, bo, (float*)d_out);
}

// Round 4
// 137.129 us; speedup vs baseline: 1.9230x; 1.0783x over previous
//
#include <hip/hip_runtime.h>
#include <hip/hip_bf16.h>

// bs=2, seq=2048, d_model=512, heads=8, d_k=64, WINDOW=2
#define SEQ 2048
#define DM  512
#define BS  2
#define NH  8
#define DK  64
#define MROWS (BS * SEQ)   // 4096
#define GK 64              // K-tile (two 16x16x32 MFMA k-steps per barrier pair)

typedef __attribute__((ext_vector_type(8))) short bf16x8;
typedef __attribute__((ext_vector_type(4))) float f32x4;

__device__ __forceinline__ unsigned short f2bf(float f) {
    unsigned int u = __float_as_uint(f);
    u += 0x7fff + ((u >> 16) & 1);
    return (unsigned short)(u >> 16);
}

// async global->LDS, 16B per lane. LDS dest must be wave-uniform base + lane*16.
#define GLDS16(g, l) __builtin_amdgcn_global_load_lds( \
    (const __attribute__((address_space(1))) void*)(g), \
    (__attribute__((address_space(3))) void*)(unsigned int)(unsigned long long)(l), 16, 0, 0)

// ---------------- prep: cvt q,k,v -> bf16; transpose+cvt weights; init vsum = SEQ*bv ----------------
__global__ __launch_bounds__(256) void prep_kernel(const float* __restrict__ q,
                                                   const float* __restrict__ k,
                                                   const float* __restrict__ v,
                                                   const float* __restrict__ Wq, const float* __restrict__ Wk,
                                                   const float* __restrict__ Wv, const float* __restrict__ Wo,
                                                   const float* __restrict__ bv_,
                                                   unsigned short* __restrict__ qb,
                                                   unsigned short* __restrict__ kb,
                                                   unsigned short* __restrict__ vb,
                                                   unsigned short* __restrict__ WqT, unsigned short* __restrict__ WkT,
                                                   unsigned short* __restrict__ WvT, unsigned short* __restrict__ WoT,
                                                   float* __restrict__ vsum)
{
    __shared__ float tile[32][33];
    const int bid = blockIdx.x;
    if (bid == 0) {
        // vsum[b*DM + c] = SEQ * bv[c]  (bias contribution to the V column-sum)
        #pragma unroll
        for (int t = 0; t < 4; ++t) {
            const int idx = threadIdx.x * 4 + t;           // 0..1023
            vsum[idx] = (float)SEQ * bv_[idx & (DM - 1)];
        }
    }
    if (bid < 3072) {
        const int z = bid >> 10;
        const int blk = bid & 1023;
        const float* src = (z == 0) ? q : (z == 1) ? k : v;
        unsigned short* dst = (z == 0) ? qb : (z == 1) ? kb : vb;
        const size_t idx = ((size_t)blk * 256 + threadIdx.x) * 8;
        float4 v0 = *(const float4*)(src + idx);
        float4 v1 = *(const float4*)(src + idx + 4);
        ushort4 o0, o1;
        o0.x = f2bf(v0.x); o0.y = f2bf(v0.y); o0.z = f2bf(v0.z); o0.w = f2bf(v0.w);
        o1.x = f2bf(v1.x); o1.y = f2bf(v1.y); o1.z = f2bf(v1.z); o1.w = f2bf(v1.w);
        *(ushort4*)(dst + idx) = o0;
        *(ushort4*)(dst + idx + 4) = o1;
    } else {
        const int t = bid - 3072;
        const int z = t >> 8;
        const int tl = t & 255;
        const float* W = (z == 0) ? Wq : (z == 1) ? Wk : (z == 2) ? Wv : Wo;
        unsigned short* T = (z == 0) ? WqT : (z == 1) ? WkT : (z == 2) ? WvT : WoT;
        const int n0 = (tl & 15) * 32, k0 = (tl >> 4) * 32;
        const int tx = threadIdx.x & 31;
        const int ty = threadIdx.x >> 5;
        #pragma unroll
        for (int r = 0; r < 32; r += 8)
            tile[ty + r][tx] = W[(size_t)(k0 + ty + r) * DM + n0 + tx];
        __syncthreads();
        #pragma unroll
        for (int r = 0; r < 32; r += 8)
            T[(size_t)(n0 + ty + r) * DM + k0 + tx] = f2bf(tile[tx][ty + r]);
    }
}

// ---------------- templated bf16 MFMA GEMM core, GK=64 ----------------
// C(f32, M x 512) = A(bf16, M x 512) @ BT(bf16, 512 x 512)^T + bias
// LDS layout: A region [kk][row][32], then B region [kk][row][32] (row stride 64B,
// m97 bank behavior). Chunk->global mapping permuted so LDS dests stay contiguous
// (global_load_lds requirement: dest = uniform base + lane*16).
// If vsumP != null, also atomically accumulates per-column sums of the raw GEMM
// (bias excluded; folded into vsum init) into vsumP[b*DM + col].
template<int TGM, int TGN, int WMT, int WNT>
__device__ __forceinline__ void gemm_core(const unsigned short* __restrict__ A,
                                          const unsigned short* __restrict__ BT,
                                          const float* __restrict__ bias,
                                          float* __restrict__ C,
                                          float* __restrict__ vsumP)
{
    __shared__ unsigned short S[(TGM + TGN) * GK];

    const int tid  = threadIdx.x;
    const int lane = tid & 63;
    const int wave = tid >> 6;
    constexpr int WAVES_M = TGM / (WMT * 16);
    const int wm = (wave % WAVES_M) * (WMT * 16);
    const int wn = (wave / WAVES_M) * (WNT * 16);
    const int m0 = blockIdx.y * TGM;
    const int n0 = blockIdx.x * TGN;
    const int l15 = lane & 15;
    const int q8  = (lane >> 4) * 8;

    f32x4 acc[WMT][WNT];
    #pragma unroll
    for (int i = 0; i < WMT; ++i)
        #pragma unroll
        for (int j = 0; j < WNT; ++j)
            acc[i][j] = (f32x4){0.f, 0.f, 0.f, 0.f};

    constexpr int NCH = (TGM + TGN) * 8;   // 16B chunks per GK-tile
    constexpr int NIT = NCH / 256;
    const unsigned short* gp[NIT];
    unsigned short* lp[NIT];
    #pragma unroll
    for (int it = 0; it < NIT; ++it) {
        const int c = tid + it * 256;
        if (c < TGM * 8) {
            const int kk = c / (TGM * 4);
            const int cr = c - kk * (TGM * 4);
            gp[it] = A + (size_t)(m0 + (cr >> 2)) * DM + kk * 32 + (cr & 3) * 8;
        } else {
            const int cb = c - TGM * 8;
            const int kk = cb / (TGN * 4);
            const int cr = cb - kk * (TGN * 4);
            gp[it] = BT + (size_t)(n0 + (cr >> 2)) * DM + kk * 32 + (cr & 3) * 8;
        }
        lp[it] = &S[(size_t)c * 8];
    }

    for (int k0 = 0; k0 < DM; k0 += GK) {
        #pragma unroll
        for (int it = 0; it < NIT; ++it)
            GLDS16(gp[it] + k0, lp[it]);
        __syncthreads();

        #pragma unroll
        for (int kk = 0; kk < 2; ++kk) {
            bf16x8 af[WMT], bfr[WNT];
            #pragma unroll
            for (int i = 0; i < WMT; ++i)
                af[i] = *(const bf16x8*)&S[kk * TGM * 32 + (wm + i * 16 + l15) * 32 + q8];
            #pragma unroll
            for (int j = 0; j < WNT; ++j)
                bfr[j] = *(const bf16x8*)&S[TGM * 64 + kk * TGN * 32 + (wn + j * 16 + l15) * 32 + q8];
            #pragma unroll
            for (int i = 0; i < WMT; ++i)
                #pragma unroll
                for (int j = 0; j < WNT; ++j)
                    acc[i][j] = __builtin_amdgcn_mfma_f32_16x16x32_bf16(af[i], bfr[j], acc[i][j], 0, 0, 0);
        }
        __syncthreads();
    }

    // epilogue: C/D layout col=lane&15, row=(lane>>4)*4+reg
    #pragma unroll
    for (int j = 0; j < WNT; ++j) {
        const int col = n0 + wn + j * 16 + l15;
        const float bv = bias[col];
        #pragma unroll
        for (int i = 0; i < WMT; ++i) {
            const int rbase = m0 + wm + i * 16 + (lane >> 4) * 4;
            #pragma unroll
            for (int r = 0; r < 4; ++r)
                C[(size_t)(rbase + r) * DM + col] = acc[i][j][r] + bv;
        }
    }

    if (vsumP) {
        const int b = m0 >> 11;   // m0 / SEQ (tile never straddles the batch boundary)
        #pragma unroll
        for (int j = 0; j < WNT; ++j) {
            float part = 0.f;
            #pragma unroll
            for (int i = 0; i < WMT; ++i)
                #pragma unroll
                for (int r = 0; r < 4; ++r)
                    part += acc[i][j][r];
            // sum the 4 lane-groups (lanes differing in bits 4,5) sharing this column
            part += __shfl_xor(part, 16, 64);
            part += __shfl_xor(part, 32, 64);
            if ((lane >> 4) == 0)
                atomicAdd(&vsumP[b * DM + wn + n0 + j * 16 + l15], part);
        }
    }
}

// qkv: 128x64 tile, grid (8, 32, 3) = 768 blocks (3/CU), wave = 64x32
__global__ __launch_bounds__(256) void gemm_qkv(const unsigned short* qb, const unsigned short* kb, const unsigned short* vb,
                                                const unsigned short* WqT, const unsigned short* WkT, const unsigned short* WvT,
                                                const float* bq, const float* bk, const float* bv,
                                                float* Qp, float* Kp, float* Vp, float* vsum)
{
    const unsigned short* A;  const unsigned short* BT;  const float* bias;  float* C;  float* vs;
    if (blockIdx.z == 0)      { A = qb; BT = WqT; bias = bq; C = Qp; vs = nullptr; }
    else if (blockIdx.z == 1) { A = kb; BT = WkT; bias = bk; C = Kp; vs = nullptr; }
    else                      { A = vb; BT = WvT; bias = bv; C = Vp; vs = vsum; }
    gemm_core<128, 64, 4, 2>(A, BT, bias, C, vs);
}

// out: 64x64 tile, grid (8, 64) = 512 blocks (2/CU), wave = 32x32
__global__ __launch_bounds__(256) void gemm_out(const unsigned short* A, const unsigned short* BT,
                                                const float* bias, float* C)
{
    gemm_core<64, 64, 2, 2>(A, BT, bias, C, nullptr);
}

// ---------------- band attention, full-row-softmax algebra, bf16 concat out ----------------
// out_row = (vsum + sum_band (e^s - 1) v_k) / (seq + sum_band (e^s - 1))
__global__ __launch_bounds__(256) void attn_kernel(const float* __restrict__ Qp,
                                                   const float* __restrict__ Kp,
                                                   const float* __restrict__ Vp,
                                                   const float* __restrict__ vsum,
                                                   unsigned short* __restrict__ concat)
{
    const int d = threadIdx.x;                      // 0..63
    const int qpos = blockIdx.x * 4 + threadIdx.y;
    const int h = blockIdx.y & 7;
    const int b = blockIdx.y >> 3;
    const int col = h * DK + d;
    const size_t rowbase = (size_t)b * SEQ;
    const float* Kcol = Kp + rowbase * DM + col;
    const float* Vcol = Vp + rowbase * DM + col;

    const float qd = Qp[(rowbase + qpos) * DM + col];
    float acc = vsum[b * DM + col];
    float den = (float)SEQ;

    float p[9], vv[9], cw[9];
    #pragma unroll
    for (int j = 0; j < 9; ++j) {
        const int k = qpos - 4 + j;
        const int kc = min(max(k, 0), SEQ - 1);
        p[j]  = qd * Kcol[(size_t)kc * DM];
        vv[j] = Vcol[(size_t)kc * DM];
        const int mn = min(qpos, k);
        const int mx = qpos + k - mn;
        const float cnt = (float)(min(mn + 2, SEQ - 1) - max(mx - 2, 0) + 1);
        cw[j] = (k >= 0 && k < SEQ) ? cnt * 0.125f : 0.0f;
    }
    #pragma unroll
    for (int off = 32; off >= 1; off >>= 1)
        #pragma unroll
        for (int j = 0; j < 9; ++j)
            p[j] += __shfl_xor(p[j], off, 64);
    #pragma unroll
    for (int j = 0; j < 9; ++j) {
        const float w = expf(p[j] * cw[j]) - 1.0f;   // cw==0 -> w==0 exactly
        acc += w * vv[j];
        den += w;
    }
    concat[(rowbase + qpos) * DM + col] = f2bf(acc / den);
}

extern "C" void kernel_launch(void* const* d_in, const int* in_sizes, int n_in,
                              void* d_out, int out_size, void* d_ws, size_t ws_size,
                              hipStream_t stream) {
    const float* q  = (const float*)d_in[0];
    const float* k  = (const float*)d_in[1];
    const float* v  = (const float*)d_in[2];
    const float* Wq = (const float*)d_in[3];
    const float* bq = (const float*)d_in[4];
    const float* Wk = (const float*)d_in[5];
    const float* bk = (const float*)d_in[6];
    const float* Wv = (const float*)d_in[7];
    const float* bv = (const float*)d_in[8];
    const float* Wo = (const float*)d_in[9];
    const float* bo = (const float*)d_in[10];

    const size_t NE = (size_t)MROWS * DM;  // 2,097,152

    float* ws = (float*)d_ws;
    float* Qp   = ws;
    float* Kp   = Qp + NE;
    float* Vp   = Kp + NE;
    float* vsum = Vp + NE;                 // 1024 floats
    unsigned short* qb     = (unsigned short*)(vsum + 1024);
    unsigned short* kb     = qb + NE;
    unsigned short* vb     = kb + NE;
    unsigned short* WqT    = vb + NE;
    unsigned short* WkT    = WqT + DM * DM;
    unsigned short* WvT    = WkT + DM * DM;
    unsigned short* WoT    = WvT + DM * DM;
    unsigned short* concat = WoT + DM * DM;

    // 1. cvt q/k/v to bf16 + weight transpose + vsum init (one dispatch)
    prep_kernel<<<4096, 256, 0, stream>>>(q, k, v, Wq, Wk, Wv, Wo, bv,
                                          qb, kb, vb, WqT, WkT, WvT, WoT, vsum);

    // 2. fused Q/K/V projection GEMMs + fused V column-sum (768 blocks, 3/CU)
    gemm_qkv<<<dim3(DM / 64, MROWS / 128, 3), 256, 0, stream>>>(qb, kb, vb, WqT, WkT, WvT,
                                                                bq, bk, bv, Qp, Kp, Vp, vsum);

    // 3. band attention -> bf16 concat
    attn_kernel<<<dim3(SEQ / 4, BS * NH), dim3(64, 4), 0, stream>>>(Qp, Kp, Vp, vsum, concat);

    // 4. output projection (512 blocks, 2/CU)
    gemm_out<<<dim3(DM / 64, MROWS / 64), 256, 0, stream>>>(concat, WoT, bo, (float*)d_out);
}

// Round 5
// 124.879 us; speedup vs baseline: 2.1116x; 1.0981x over previous
//
#include <hip/hip_runtime.h>
#include <hip/hip_bf16.h>

// bs=2, seq=2048, d_model=512, heads=8, d_k=64, WINDOW=2
#define SEQ 2048
#define DM  512
#define BS  2
#define NH  8
#define DK  64
#define MROWS (BS * SEQ)   // 4096
#define GK 64              // GEMM K-tile (two 16x16x32 MFMA k-steps per barrier pair)

typedef __attribute__((ext_vector_type(8))) short bf16x8;
typedef __attribute__((ext_vector_type(4))) float f32x4;

__device__ __forceinline__ unsigned short f2bf(float f) {
    unsigned int u = __float_as_uint(f);
    u += 0x7fff + ((u >> 16) & 1);
    return (unsigned short)(u >> 16);
}
__device__ __forceinline__ float bf2f(unsigned short b) {
    return __uint_as_float((unsigned int)b << 16);
}

// async global->LDS, 16B per lane. LDS dest must be wave-uniform base + lane*16.
#define GLDS16(g, l) __builtin_amdgcn_global_load_lds( \
    (const __attribute__((address_space(1))) void*)(g), \
    (__attribute__((address_space(3))) void*)(unsigned int)(unsigned long long)(l), 16, 0, 0)

// ---------------- prep: cvt q,k,v -> bf16; transpose+cvt weights; init vsum = SEQ*bv ----------------
__global__ __launch_bounds__(256) void prep_kernel(const float* __restrict__ q,
                                                   const float* __restrict__ k,
                                                   const float* __restrict__ v,
                                                   const float* __restrict__ Wq, const float* __restrict__ Wk,
                                                   const float* __restrict__ Wv, const float* __restrict__ Wo,
                                                   const float* __restrict__ bv_,
                                                   unsigned short* __restrict__ qb,
                                                   unsigned short* __restrict__ kb,
                                                   unsigned short* __restrict__ vb,
                                                   unsigned short* __restrict__ WqT, unsigned short* __restrict__ WkT,
                                                   unsigned short* __restrict__ WvT, unsigned short* __restrict__ WoT,
                                                   float* __restrict__ vsum)
{
    __shared__ float tile[32][33];
    const int bid = blockIdx.x;
    if (bid == 0) {
        #pragma unroll
        for (int t = 0; t < 4; ++t) {
            const int idx = threadIdx.x * 4 + t;           // 0..1023
            vsum[idx] = (float)SEQ * bv_[idx & (DM - 1)];
        }
    }
    if (bid < 3072) {
        const int z = bid >> 10;
        const int blk = bid & 1023;
        const float* src = (z == 0) ? q : (z == 1) ? k : v;
        unsigned short* dst = (z == 0) ? qb : (z == 1) ? kb : vb;
        const size_t idx = ((size_t)blk * 256 + threadIdx.x) * 8;
        float4 v0 = *(const float4*)(src + idx);
        float4 v1 = *(const float4*)(src + idx + 4);
        ushort4 o0, o1;
        o0.x = f2bf(v0.x); o0.y = f2bf(v0.y); o0.z = f2bf(v0.z); o0.w = f2bf(v0.w);
        o1.x = f2bf(v1.x); o1.y = f2bf(v1.y); o1.z = f2bf(v1.z); o1.w = f2bf(v1.w);
        *(ushort4*)(dst + idx) = o0;
        *(ushort4*)(dst + idx + 4) = o1;
    } else {
        const int t = bid - 3072;
        const int z = t >> 8;
        const int tl = t & 255;
        const float* W = (z == 0) ? Wq : (z == 1) ? Wk : (z == 2) ? Wv : Wo;
        unsigned short* T = (z == 0) ? WqT : (z == 1) ? WkT : (z == 2) ? WvT : WoT;
        const int n0 = (tl & 15) * 32, k0 = (tl >> 4) * 32;
        const int tx = threadIdx.x & 31;
        const int ty = threadIdx.x >> 5;
        #pragma unroll
        for (int r = 0; r < 32; r += 8)
            tile[ty + r][tx] = W[(size_t)(k0 + ty + r) * DM + n0 + tx];
        __syncthreads();
        #pragma unroll
        for (int r = 0; r < 32; r += 8)
            T[(size_t)(n0 + ty + r) * DM + k0 + tx] = f2bf(tile[tx][ty + r]);
    }
}

// ---------------- templated bf16 MFMA GEMM core, GK=64 ----------------
// C(M x 512) = A(bf16, M x 512) @ BT(bf16, 512 x 512)^T + bias
// BF16OUT: store C as bf16 (unsigned short*), else f32 (float*).
// If vsumP != null, atomically accumulates per-column sums of the raw f32 GEMM
// (bias excluded; folded into vsum init) into vsumP[b*DM + col].
template<int TGM, int TGN, int WMT, int WNT, bool BF16OUT>
__device__ __forceinline__ void gemm_core(const unsigned short* __restrict__ A,
                                          const unsigned short* __restrict__ BT,
                                          const float* __restrict__ bias,
                                          void* __restrict__ Cv,
                                          float* __restrict__ vsumP)
{
    __shared__ unsigned short S[(TGM + TGN) * GK];

    const int tid  = threadIdx.x;
    const int lane = tid & 63;
    const int wave = tid >> 6;
    constexpr int WAVES_M = TGM / (WMT * 16);
    const int wm = (wave % WAVES_M) * (WMT * 16);
    const int wn = (wave / WAVES_M) * (WNT * 16);
    const int m0 = blockIdx.y * TGM;
    const int n0 = blockIdx.x * TGN;
    const int l15 = lane & 15;
    const int q8  = (lane >> 4) * 8;

    f32x4 acc[WMT][WNT];
    #pragma unroll
    for (int i = 0; i < WMT; ++i)
        #pragma unroll
        for (int j = 0; j < WNT; ++j)
            acc[i][j] = (f32x4){0.f, 0.f, 0.f, 0.f};

    constexpr int NCH = (TGM + TGN) * 8;   // 16B chunks per GK-tile
    constexpr int NIT = NCH / 256;
    const unsigned short* gp[NIT];
    unsigned short* lp[NIT];
    #pragma unroll
    for (int it = 0; it < NIT; ++it) {
        const int c = tid + it * 256;
        if (c < TGM * 8) {
            const int kk = c / (TGM * 4);
            const int cr = c - kk * (TGM * 4);
            gp[it] = A + (size_t)(m0 + (cr >> 2)) * DM + kk * 32 + (cr & 3) * 8;
        } else {
            const int cb = c - TGM * 8;
            const int kk = cb / (TGN * 4);
            const int cr = cb - kk * (TGN * 4);
            gp[it] = BT + (size_t)(n0 + (cr >> 2)) * DM + kk * 32 + (cr & 3) * 8;
        }
        lp[it] = &S[(size_t)c * 8];
    }

    for (int k0 = 0; k0 < DM; k0 += GK) {
        #pragma unroll
        for (int it = 0; it < NIT; ++it)
            GLDS16(gp[it] + k0, lp[it]);
        __syncthreads();

        #pragma unroll
        for (int kk = 0; kk < 2; ++kk) {
            bf16x8 af[WMT], bfr[WNT];
            #pragma unroll
            for (int i = 0; i < WMT; ++i)
                af[i] = *(const bf16x8*)&S[kk * TGM * 32 + (wm + i * 16 + l15) * 32 + q8];
            #pragma unroll
            for (int j = 0; j < WNT; ++j)
                bfr[j] = *(const bf16x8*)&S[TGM * 64 + kk * TGN * 32 + (wn + j * 16 + l15) * 32 + q8];
            #pragma unroll
            for (int i = 0; i < WMT; ++i)
                #pragma unroll
                for (int j = 0; j < WNT; ++j)
                    acc[i][j] = __builtin_amdgcn_mfma_f32_16x16x32_bf16(af[i], bfr[j], acc[i][j], 0, 0, 0);
        }
        __syncthreads();
    }

    // epilogue: C/D layout col=lane&15, row=(lane>>4)*4+reg
    #pragma unroll
    for (int j = 0; j < WNT; ++j) {
        const int col = n0 + wn + j * 16 + l15;
        const float bv = bias[col];
        #pragma unroll
        for (int i = 0; i < WMT; ++i) {
            const int rbase = m0 + wm + i * 16 + (lane >> 4) * 4;
            #pragma unroll
            for (int r = 0; r < 4; ++r) {
                const float val = acc[i][j][r] + bv;
                if (BF16OUT)
                    ((unsigned short*)Cv)[(size_t)(rbase + r) * DM + col] = f2bf(val);
                else
                    ((float*)Cv)[(size_t)(rbase + r) * DM + col] = val;
            }
        }
    }

    if (vsumP) {
        const int b = m0 >> 11;   // m0 / SEQ (tile never straddles the batch boundary)
        #pragma unroll
        for (int j = 0; j < WNT; ++j) {
            float part = 0.f;
            #pragma unroll
            for (int i = 0; i < WMT; ++i)
                #pragma unroll
                for (int r = 0; r < 4; ++r)
                    part += acc[i][j][r];
            part += __shfl_xor(part, 16, 64);
            part += __shfl_xor(part, 32, 64);
            if ((lane >> 4) == 0)
                atomicAdd(&vsumP[b * DM + wn + n0 + j * 16 + l15], part);
        }
    }
}

// qkv: 128x64 tile, grid (8, 32, 3) = 768 blocks, bf16 output
__global__ __launch_bounds__(256) void gemm_qkv(const unsigned short* qb, const unsigned short* kb, const unsigned short* vb,
                                                const unsigned short* WqT, const unsigned short* WkT, const unsigned short* WvT,
                                                const float* bq, const float* bk, const float* bv,
                                                unsigned short* Qb, unsigned short* Kb, unsigned short* Vb, float* vsum)
{
    const unsigned short* A;  const unsigned short* BT;  const float* bias;  unsigned short* C;  float* vs;
    if (blockIdx.z == 0)      { A = qb; BT = WqT; bias = bq; C = Qb; vs = nullptr; }
    else if (blockIdx.z == 1) { A = kb; BT = WkT; bias = bk; C = Kb; vs = nullptr; }
    else                      { A = vb; BT = WvT; bias = bv; C = Vb; vs = vsum; }
    gemm_core<128, 64, 4, 2, true>(A, BT, bias, C, vs);
}

// out: 64x64 tile, grid (8, 64) = 512 blocks, f32 output
__global__ __launch_bounds__(256) void gemm_out(const unsigned short* A, const unsigned short* BT,
                                                const float* bias, float* C)
{
    gemm_core<64, 64, 2, 2, false>(A, BT, bias, C, nullptr);
}

// ---------------- MFMA band attention ----------------
// One wave per (b,h, 16-q tile). QK^T: 2 n-tiles x 2 k-steps of 16x16x32 bf16.
// w = exp(s*cnt/8)-1 on C-frag; den via 4-level shuffle over the 16-lane col group;
// W -> A-frag via 1KB LDS round-trip; PV: 4 n-tiles x 1 k-step (kpos window 24+8pad).
// out_row = (vsum + sum_band w*v) / (SEQ + sum_band w)
__global__ __launch_bounds__(64) void attn_mfma(const unsigned short* __restrict__ Qb,
                                                const unsigned short* __restrict__ Kb,
                                                const unsigned short* __restrict__ Vb,
                                                const float* __restrict__ vsum,
                                                unsigned short* __restrict__ concat)
{
    __shared__ unsigned short Wlds[16 * 32];   // [q_local][kpos_local]
    const int lane = threadIdx.x;              // 0..63
    const int l15  = lane & 15;
    const int quad = lane >> 4;                // 0..3
    const int bh = blockIdx.y;
    const int b = bh >> 3, h = bh & 7;
    const int q0 = blockIdx.x * 16;
    const size_t rowbase = (size_t)b * SEQ;
    const int dbase = h * DK;

    // Q A-frags (m=l15 -> q0+m, k=quad*8+j over d; 2 k-steps)
    const unsigned short* qrow = Qb + (rowbase + q0 + l15) * DM + dbase + quad * 8;
    const bf16x8 aq0 = *(const bf16x8*)(qrow);
    const bf16x8 aq1 = *(const bf16x8*)(qrow + 32);

    // QK^T: n-tile t covers kpos = q0-4+t*16+n (n=l15); OOB clamped, masked later
    f32x4 sc[2];
    #pragma unroll
    for (int t = 0; t < 2; ++t) {
        int kp = q0 - 4 + t * 16 + l15;
        kp = min(max(kp, 0), SEQ - 1);
        const unsigned short* krow = Kb + (rowbase + kp) * DM + dbase + quad * 8;
        const bf16x8 b0 = *(const bf16x8*)(krow);
        const bf16x8 b1 = *(const bf16x8*)(krow + 32);
        f32x4 z = (f32x4){0.f, 0.f, 0.f, 0.f};
        z = __builtin_amdgcn_mfma_f32_16x16x32_bf16(aq0, b0, z, 0, 0, 0);
        sc[t] = __builtin_amdgcn_mfma_f32_16x16x32_bf16(aq1, b1, sc[t] = z, 0, 0, 0);
    }

    // weights (bf16-rounded; den summed from rounded values for consistency)
    float dsum[4] = {0.f, 0.f, 0.f, 0.f};
    #pragma unroll
    for (int t = 0; t < 2; ++t) {
        const int kpos = q0 - 4 + t * 16 + l15;   // unclamped
        #pragma unroll
        for (int r = 0; r < 4; ++r) {
            const int qq = q0 + quad * 4 + r;
            const int mn = min(qq, kpos), mx = qq + kpos - mn;
            const float cnt = (float)(min(mn + 2, SEQ - 1) - max(mx - 2, 0) + 1);
            const float cw = (kpos >= 0 && kpos < SEQ && (mx - mn) <= 4) ? cnt * 0.125f : 0.f;
            const float w = expf(sc[t][r] * cw) - 1.f;   // cw==0 -> exactly 0
            const unsigned short wb = f2bf(w);
            Wlds[(quad * 4 + r) * 32 + t * 16 + l15] = wb;
            dsum[r] += bf2f(wb);
        }
    }
    #pragma unroll
    for (int off = 1; off <= 8; off <<= 1)
        #pragma unroll
        for (int r = 0; r < 4; ++r)
            dsum[r] += __shfl_xor(dsum[r], off, 64);

    __syncthreads();
    // W A-frag: m=l15 (q_local), k=quad*8+j (kpos_local), single k=32 step
    const bf16x8 aw = *(const bf16x8*)&Wlds[l15 * 32 + quad * 8];

    // PV + epilogue, 4 n-tiles over d
    #pragma unroll
    for (int nt = 0; nt < 4; ++nt) {
        const int d = dbase + nt * 16 + l15;
        bf16x8 bv_;
        #pragma unroll
        for (int j = 0; j < 8; ++j) {
            int kr = q0 - 4 + quad * 8 + j;      // kpos_local = quad*8+j
            kr = min(max(kr, 0), SEQ - 1);       // pad rows get w=0
            bv_[j] = (short)Vb[(rowbase + kr) * DM + d];
        }
        f32x4 z = (f32x4){0.f, 0.f, 0.f, 0.f};
        const f32x4 o = __builtin_amdgcn_mfma_f32_16x16x32_bf16(aw, bv_, z, 0, 0, 0);
        const float vs = vsum[b * DM + d];
        #pragma unroll
        for (int r = 0; r < 4; ++r) {
            const float den = (float)SEQ + dsum[r];
            concat[(rowbase + q0 + quad * 4 + r) * DM + d] = f2bf((vs + o[r]) / den);
        }
    }
}

extern "C" void kernel_launch(void* const* d_in, const int* in_sizes, int n_in,
                              void* d_out, int out_size, void* d_ws, size_t ws_size,
                              hipStream_t stream) {
    const float* q  = (const float*)d_in[0];
    const float* k  = (const float*)d_in[1];
    const float* v  = (const float*)d_in[2];
    const float* Wq = (const float*)d_in[3];
    const float* bq = (const float*)d_in[4];
    const float* Wk = (const float*)d_in[5];
    const float* bk = (const float*)d_in[6];
    const float* Wv = (const float*)d_in[7];
    const float* bv = (const float*)d_in[8];
    const float* Wo = (const float*)d_in[9];
    const float* bo = (const float*)d_in[10];

    const size_t NE = (size_t)MROWS * DM;  // 2,097,152

    float* vsum = (float*)d_ws;                        // 1024 floats
    unsigned short* Qb     = (unsigned short*)(vsum + 1024);
    unsigned short* Kb     = Qb + NE;
    unsigned short* Vb     = Kb + NE;
    unsigned short* qb     = Vb + NE;
    unsigned short* kb     = qb + NE;
    unsigned short* vb     = kb + NE;
    unsigned short* WqT    = vb + NE;
    unsigned short* WkT    = WqT + DM * DM;
    unsigned short* WvT    = WkT + DM * DM;
    unsigned short* WoT    = WvT + DM * DM;
    unsigned short* concat = WoT + DM * DM;

    // 1. cvt q/k/v to bf16 + weight transpose + vsum init
    prep_kernel<<<4096, 256, 0, stream>>>(q, k, v, Wq, Wk, Wv, Wo, bv,
                                          qb, kb, vb, WqT, WkT, WvT, WoT, vsum);

    // 2. fused Q/K/V projection GEMMs (bf16 out) + fused V column-sum
    gemm_qkv<<<dim3(DM / 64, MROWS / 128, 3), 256, 0, stream>>>(qb, kb, vb, WqT, WkT, WvT,
                                                                bq, bk, bv, Qb, Kb, Vb, vsum);

    // 3. MFMA band attention -> bf16 concat (2048 waves, 8/CU)
    attn_mfma<<<dim3(SEQ / 16, BS * NH), 64, 0, stream>>>(Qb, Kb, Vb, vsum, concat);

    // 4. output projection (512 blocks)
    gemm_out<<<dim3(DM / 64, MROWS / 64), 256, 0, stream>>>(concat, WoT, bo, (float*)d_out);
}

// Round 6
// 123.457 us; speedup vs baseline: 2.1359x; 1.0115x over previous
//
#include <hip/hip_runtime.h>
#include <hip/hip_bf16.h>

// bs=2, seq=2048, d_model=512, heads=8, d_k=64, WINDOW=2
#define SEQ 2048
#define DM  512
#define BS  2
#define NH  8
#define DK  64
#define MROWS (BS * SEQ)   // 4096
#define GK 64              // GEMM K-tile (two 16x16x32 MFMA k-steps per barrier pair)

typedef __attribute__((ext_vector_type(8))) short bf16x8;
typedef __attribute__((ext_vector_type(4))) float f32x4;

__device__ __forceinline__ unsigned short f2bf(float f) {
    unsigned int u = __float_as_uint(f);
    u += 0x7fff + ((u >> 16) & 1);
    return (unsigned short)(u >> 16);
}
__device__ __forceinline__ float bf2f(unsigned short b) {
    return __uint_as_float((unsigned int)b << 16);
}

// async global->LDS, 16B per lane. LDS dest must be wave-uniform base + lane*16.
#define GLDS16(g, l) __builtin_amdgcn_global_load_lds( \
    (const __attribute__((address_space(1))) void*)(g), \
    (__attribute__((address_space(3))) void*)(unsigned int)(unsigned long long)(l), 16, 0, 0)

// ---------------- prep (small): transpose+cvt weights; init vsum = SEQ*bv ----------------
__global__ __launch_bounds__(256) void prep_w(const float* __restrict__ Wq, const float* __restrict__ Wk,
                                              const float* __restrict__ Wv, const float* __restrict__ Wo,
                                              const float* __restrict__ bv_,
                                              unsigned short* __restrict__ WqT, unsigned short* __restrict__ WkT,
                                              unsigned short* __restrict__ WvT, unsigned short* __restrict__ WoT,
                                              float* __restrict__ vsum)
{
    __shared__ float tile[32][33];
    const int bid = blockIdx.x;            // 0..1023
    if (bid == 0) {
        #pragma unroll
        for (int t = 0; t < 4; ++t) {
            const int idx = threadIdx.x * 4 + t;           // 0..1023
            vsum[idx] = (float)SEQ * bv_[idx & (DM - 1)];
        }
    }
    const int z = bid >> 8;
    const int tl = bid & 255;
    const float* W = (z == 0) ? Wq : (z == 1) ? Wk : (z == 2) ? Wv : Wo;
    unsigned short* T = (z == 0) ? WqT : (z == 1) ? WkT : (z == 2) ? WvT : WoT;
    const int n0 = (tl & 15) * 32, k0 = (tl >> 4) * 32;
    const int tx = threadIdx.x & 31;
    const int ty = threadIdx.x >> 5;
    #pragma unroll
    for (int r = 0; r < 32; r += 8)
        tile[ty + r][tx] = W[(size_t)(k0 + ty + r) * DM + n0 + tx];
    __syncthreads();
    #pragma unroll
    for (int r = 0; r < 32; r += 8)
        T[(size_t)(n0 + ty + r) * DM + k0 + tx] = f2bf(tile[tx][ty + r]);
}

// ---------------- QKV projection GEMM with fused f32->bf16 A-staging ----------------
// C(bf16, 4096x512) = cvt_bf16(A f32) @ BT(bf16)^T + bias.  Tile 128x128, GK=64.
// A staged via registers (load f32 -> RNE cvt -> ds_write_b64); B via global_load_lds.
// z==2 (V) also accumulates raw per-column sums into vsum (bias pre-folded).
__global__ __launch_bounds__(256) void gemm_qkv_cvt(const float* __restrict__ q,
                                                    const float* __restrict__ k,
                                                    const float* __restrict__ v,
                                                    const unsigned short* __restrict__ WqT,
                                                    const unsigned short* __restrict__ WkT,
                                                    const unsigned short* __restrict__ WvT,
                                                    const float* __restrict__ bq, const float* __restrict__ bk,
                                                    const float* __restrict__ bvp,
                                                    unsigned short* __restrict__ Qb, unsigned short* __restrict__ Kb,
                                                    unsigned short* __restrict__ Vb, float* __restrict__ vsum)
{
    __shared__ unsigned short S[256 * GK];   // A: [0,8192) shorts as [kk][row128][32]; B at 8192 same layout

    const float* Af; const unsigned short* BT; const float* bias; unsigned short* C; float* vs;
    if (blockIdx.z == 0)      { Af = q; BT = WqT; bias = bq; C = Qb; vs = nullptr; }
    else if (blockIdx.z == 1) { Af = k; BT = WkT; bias = bk; C = Kb; vs = nullptr; }
    else                      { Af = v; BT = WvT; bias = bvp; C = Vb; vs = vsum; }

    const int tid  = threadIdx.x;
    const int lane = tid & 63;
    const int wave = tid >> 6;
    const int wm = (wave & 1) * 64;
    const int wn = (wave >> 1) * 64;
    const int m0 = blockIdx.y * 128;
    const int n0 = blockIdx.x * 128;
    const int l15 = lane & 15;
    const int q8  = (lane >> 4) * 8;

    f32x4 acc[4][4];
    #pragma unroll
    for (int i = 0; i < 4; ++i)
        #pragma unroll
        for (int j = 0; j < 4; ++j)
            acc[i][j] = (f32x4){0.f, 0.f, 0.f, 0.f};

    // A-staging mapping: pass p covers rows p*16 + (tid>>4), cols (tid&15)*4 .. +3
    const int arow = tid >> 4;             // 0..15
    const int akl  = (tid & 15) * 4;       // 0..60
    const int awoff = ((akl >> 5) * 4096) + (akl & 31);   // + row*32 (shorts)

    // B chunks: 1024 x 16B per K-tile, 4 per thread
    const unsigned short* gb[4];
    unsigned short* lb[4];
    #pragma unroll
    for (int it = 0; it < 4; ++it) {
        const int c = tid + it * 256;
        const int n  = (c >> 2) & 127;
        const int kk = c >> 9;
        gb[it] = BT + (size_t)(n0 + n) * DM + kk * 32 + (c & 3) * 8;
        lb[it] = &S[8192 + c * 8];
    }

    for (int k0 = 0; k0 < DM; k0 += GK) {
        #pragma unroll
        for (int it = 0; it < 4; ++it)
            GLDS16(gb[it] + k0, lb[it]);

        float4 av[8];
        #pragma unroll
        for (int p = 0; p < 8; ++p)
            av[p] = *(const float4*)(Af + (size_t)(m0 + p * 16 + arow) * DM + k0 + akl);
        #pragma unroll
        for (int p = 0; p < 8; ++p) {
            ushort4 o;
            o.x = f2bf(av[p].x); o.y = f2bf(av[p].y); o.z = f2bf(av[p].z); o.w = f2bf(av[p].w);
            *(ushort4*)&S[awoff + (p * 16 + arow) * 32] = o;
        }
        __syncthreads();

        #pragma unroll
        for (int kk = 0; kk < 2; ++kk) {
            bf16x8 af[4], bfr[4];
            #pragma unroll
            for (int i = 0; i < 4; ++i)
                af[i] = *(const bf16x8*)&S[kk * 4096 + (wm + i * 16 + l15) * 32 + q8];
            #pragma unroll
            for (int j = 0; j < 4; ++j)
                bfr[j] = *(const bf16x8*)&S[8192 + kk * 4096 + (wn + j * 16 + l15) * 32 + q8];
            #pragma unroll
            for (int i = 0; i < 4; ++i)
                #pragma unroll
                for (int j = 0; j < 4; ++j)
                    acc[i][j] = __builtin_amdgcn_mfma_f32_16x16x32_bf16(af[i], bfr[j], acc[i][j], 0, 0, 0);
        }
        __syncthreads();
    }

    // epilogue: C/D layout col=lane&15, row=(lane>>4)*4+reg; bf16 store
    #pragma unroll
    for (int j = 0; j < 4; ++j) {
        const int col = n0 + wn + j * 16 + l15;
        const float bv = bias[col];
        #pragma unroll
        for (int i = 0; i < 4; ++i) {
            const int rbase = m0 + wm + i * 16 + (lane >> 4) * 4;
            #pragma unroll
            for (int r = 0; r < 4; ++r)
                C[(size_t)(rbase + r) * DM + col] = f2bf(acc[i][j][r] + bv);
        }
    }

    if (vs) {
        const int b = m0 >> 11;   // tile never straddles batch boundary (16 tiles/batch)
        #pragma unroll
        for (int j = 0; j < 4; ++j) {
            float part = 0.f;
            #pragma unroll
            for (int i = 0; i < 4; ++i)
                #pragma unroll
                for (int r = 0; r < 4; ++r)
                    part += acc[i][j][r];
            part += __shfl_xor(part, 16, 64);
            part += __shfl_xor(part, 32, 64);
            if ((lane >> 4) == 0)
                atomicAdd(&vs[b * DM + n0 + wn + j * 16 + l15], part);
        }
    }
}

// ---------------- bf16 MFMA GEMM (all-bf16 staged via GLDS): used for output projection ----------------
template<int TGM, int TGN, int WMT, int WNT>
__device__ __forceinline__ void gemm_core(const unsigned short* __restrict__ A,
                                          const unsigned short* __restrict__ BT,
                                          const float* __restrict__ bias,
                                          float* __restrict__ C)
{
    __shared__ unsigned short S[(TGM + TGN) * GK];

    const int tid  = threadIdx.x;
    const int lane = tid & 63;
    const int wave = tid >> 6;
    constexpr int WAVES_M = TGM / (WMT * 16);
    const int wm = (wave % WAVES_M) * (WMT * 16);
    const int wn = (wave / WAVES_M) * (WNT * 16);
    const int m0 = blockIdx.y * TGM;
    const int n0 = blockIdx.x * TGN;
    const int l15 = lane & 15;
    const int q8  = (lane >> 4) * 8;

    f32x4 acc[WMT][WNT];
    #pragma unroll
    for (int i = 0; i < WMT; ++i)
        #pragma unroll
        for (int j = 0; j < WNT; ++j)
            acc[i][j] = (f32x4){0.f, 0.f, 0.f, 0.f};

    constexpr int NCH = (TGM + TGN) * 8;
    constexpr int NIT = NCH / 256;
    const unsigned short* gp[NIT];
    unsigned short* lp[NIT];
    #pragma unroll
    for (int it = 0; it < NIT; ++it) {
        const int c = tid + it * 256;
        if (c < TGM * 8) {
            const int kk = c / (TGM * 4);
            const int cr = c - kk * (TGM * 4);
            gp[it] = A + (size_t)(m0 + (cr >> 2)) * DM + kk * 32 + (cr & 3) * 8;
        } else {
            const int cb = c - TGM * 8;
            const int kk = cb / (TGN * 4);
            const int cr = cb - kk * (TGN * 4);
            gp[it] = BT + (size_t)(n0 + (cr >> 2)) * DM + kk * 32 + (cr & 3) * 8;
        }
        lp[it] = &S[(size_t)c * 8];
    }

    for (int k0 = 0; k0 < DM; k0 += GK) {
        #pragma unroll
        for (int it = 0; it < NIT; ++it)
            GLDS16(gp[it] + k0, lp[it]);
        __syncthreads();

        #pragma unroll
        for (int kk = 0; kk < 2; ++kk) {
            bf16x8 af[WMT], bfr[WNT];
            #pragma unroll
            for (int i = 0; i < WMT; ++i)
                af[i] = *(const bf16x8*)&S[kk * TGM * 32 + (wm + i * 16 + l15) * 32 + q8];
            #pragma unroll
            for (int j = 0; j < WNT; ++j)
                bfr[j] = *(const bf16x8*)&S[TGM * 64 + kk * TGN * 32 + (wn + j * 16 + l15) * 32 + q8];
            #pragma unroll
            for (int i = 0; i < WMT; ++i)
                #pragma unroll
                for (int j = 0; j < WNT; ++j)
                    acc[i][j] = __builtin_amdgcn_mfma_f32_16x16x32_bf16(af[i], bfr[j], acc[i][j], 0, 0, 0);
        }
        __syncthreads();
    }

    #pragma unroll
    for (int j = 0; j < WNT; ++j) {
        const int col = n0 + wn + j * 16 + l15;
        const float bv = bias[col];
        #pragma unroll
        for (int i = 0; i < WMT; ++i) {
            const int rbase = m0 + wm + i * 16 + (lane >> 4) * 4;
            #pragma unroll
            for (int r = 0; r < 4; ++r)
                C[(size_t)(rbase + r) * DM + col] = acc[i][j][r] + bv;
        }
    }
}

// out: 64x64 tile, grid (8, 64) = 512 blocks, f32 output
__global__ __launch_bounds__(256) void gemm_out(const unsigned short* A, const unsigned short* BT,
                                                const float* bias, float* C)
{
    gemm_core<64, 64, 2, 2>(A, BT, bias, C);
}

// ---------------- MFMA band attention ----------------
// One wave per (b,h, 16-q tile). QK^T: 2 n-tiles x 2 k-steps of 16x16x32 bf16.
// w = exp(s*cnt/8)-1 on C-frag; den via 4-level shuffle; W -> A-frag via 1KB LDS;
// PV: 4 n-tiles x 1 k-step.  out_row = (vsum + sum w*v) / (SEQ + sum w)
__global__ __launch_bounds__(64) void attn_mfma(const unsigned short* __restrict__ Qb,
                                                const unsigned short* __restrict__ Kb,
                                                const unsigned short* __restrict__ Vb,
                                                const float* __restrict__ vsum,
                                                unsigned short* __restrict__ concat)
{
    __shared__ unsigned short Wlds[16 * 32];   // [q_local][kpos_local]
    const int lane = threadIdx.x;              // 0..63
    const int l15  = lane & 15;
    const int quad = lane >> 4;                // 0..3
    const int bh = blockIdx.y;
    const int b = bh >> 3, h = bh & 7;
    const int q0 = blockIdx.x * 16;
    const size_t rowbase = (size_t)b * SEQ;
    const int dbase = h * DK;

    const unsigned short* qrow = Qb + (rowbase + q0 + l15) * DM + dbase + quad * 8;
    const bf16x8 aq0 = *(const bf16x8*)(qrow);
    const bf16x8 aq1 = *(const bf16x8*)(qrow + 32);

    f32x4 sc[2];
    #pragma unroll
    for (int t = 0; t < 2; ++t) {
        int kp = q0 - 4 + t * 16 + l15;
        kp = min(max(kp, 0), SEQ - 1);
        const unsigned short* krow = Kb + (rowbase + kp) * DM + dbase + quad * 8;
        const bf16x8 b0 = *(const bf16x8*)(krow);
        const bf16x8 b1 = *(const bf16x8*)(krow + 32);
        f32x4 z = (f32x4){0.f, 0.f, 0.f, 0.f};
        z = __builtin_amdgcn_mfma_f32_16x16x32_bf16(aq0, b0, z, 0, 0, 0);
        sc[t] = __builtin_amdgcn_mfma_f32_16x16x32_bf16(aq1, b1, z, 0, 0, 0);
    }

    float dsum[4] = {0.f, 0.f, 0.f, 0.f};
    #pragma unroll
    for (int t = 0; t < 2; ++t) {
        const int kpos = q0 - 4 + t * 16 + l15;   // unclamped
        #pragma unroll
        for (int r = 0; r < 4; ++r) {
            const int qq = q0 + quad * 4 + r;
            const int mn = min(qq, kpos), mx = qq + kpos - mn;
            const float cnt = (float)(min(mn + 2, SEQ - 1) - max(mx - 2, 0) + 1);
            const float cw = (kpos >= 0 && kpos < SEQ && (mx - mn) <= 4) ? cnt * 0.125f : 0.f;
            const float w = expf(sc[t][r] * cw) - 1.f;   // cw==0 -> exactly 0
            const unsigned short wb = f2bf(w);
            Wlds[(quad * 4 + r) * 32 + t * 16 + l15] = wb;
            dsum[r] += bf2f(wb);
        }
    }
    #pragma unroll
    for (int off = 1; off <= 8; off <<= 1)
        #pragma unroll
        for (int r = 0; r < 4; ++r)
            dsum[r] += __shfl_xor(dsum[r], off, 64);

    __syncthreads();
    const bf16x8 aw = *(const bf16x8*)&Wlds[l15 * 32 + quad * 8];

    #pragma unroll
    for (int nt = 0; nt < 4; ++nt) {
        const int d = dbase + nt * 16 + l15;
        bf16x8 bv_;
        #pragma unroll
        for (int j = 0; j < 8; ++j) {
            int kr = q0 - 4 + quad * 8 + j;
            kr = min(max(kr, 0), SEQ - 1);       // pad rows get w=0
            bv_[j] = (short)Vb[(rowbase + kr) * DM + d];
        }
        f32x4 z = (f32x4){0.f, 0.f, 0.f, 0.f};
        const f32x4 o = __builtin_amdgcn_mfma_f32_16x16x32_bf16(aw, bv_, z, 0, 0, 0);
        const float vs = vsum[b * DM + d];
        #pragma unroll
        for (int r = 0; r < 4; ++r) {
            const float den = (float)SEQ + dsum[r];
            concat[(rowbase + q0 + quad * 4 + r) * DM + d] = f2bf((vs + o[r]) / den);
        }
    }
}

extern "C" void kernel_launch(void* const* d_in, const int* in_sizes, int n_in,
                              void* d_out, int out_size, void* d_ws, size_t ws_size,
                              hipStream_t stream) {
    const float* q  = (const float*)d_in[0];
    const float* k  = (const float*)d_in[1];
    const float* v  = (const float*)d_in[2];
    const float* Wq = (const float*)d_in[3];
    const float* bq = (const float*)d_in[4];
    const float* Wk = (const float*)d_in[5];
    const float* bk = (const float*)d_in[6];
    const float* Wv = (const float*)d_in[7];
    const float* bv = (const float*)d_in[8];
    const float* Wo = (const float*)d_in[9];
    const float* bo = (const float*)d_in[10];

    const size_t NE = (size_t)MROWS * DM;  // 2,097,152

    float* vsum = (float*)d_ws;                        // 1024 floats
    unsigned short* Qb     = (unsigned short*)(vsum + 1024);
    unsigned short* Kb     = Qb + NE;
    unsigned short* Vb     = Kb + NE;
    unsigned short* WqT    = Vb + NE;
    unsigned short* WkT    = WqT + DM * DM;
    unsigned short* WvT    = WkT + DM * DM;
    unsigned short* WoT    = WvT + DM * DM;
    unsigned short* concat = WoT + DM * DM;

    // 1. weight transpose + vsum init (small)
    prep_w<<<1024, 256, 0, stream>>>(Wq, Wk, Wv, Wo, bv, WqT, WkT, WvT, WoT, vsum);

    // 2. Q/K/V projection GEMMs with fused f32->bf16 A-staging + fused V column-sum
    gemm_qkv_cvt<<<dim3(DM / 128, MROWS / 128, 3), 256, 0, stream>>>(q, k, v, WqT, WkT, WvT,
                                                                     bq, bk, bv, Qb, Kb, Vb, vsum);

    // 3. MFMA band attention -> bf16 concat (2048 waves, 8/CU)
    attn_mfma<<<dim3(SEQ / 16, BS * NH), 64, 0, stream>>>(Qb, Kb, Vb, vsum, concat);

    // 4. output projection (512 blocks)
    gemm_out<<<dim3(DM / 64, MROWS / 64), 256, 0, stream>>>(concat, WoT, bo, (float*)d_out);
}